// Round 5
// baseline (312.039 us; speedup 1.0000x reference)
//
#include <hip/hip_runtime.h>
#include <stdint.h>

// ---- types ----
typedef short s16x8 __attribute__((ext_vector_type(8)));
typedef float f32x4 __attribute__((ext_vector_type(4)));
typedef unsigned int u32x4 __attribute__((ext_vector_type(4)));

// log2(e) / sqrt(128): fold softmax scale + exp2 conversion into Q projection
#define QSCALE 0.12751743f

__device__ __forceinline__ unsigned short f2bf(float f) {
  unsigned int u = __builtin_bit_cast(unsigned int, f);
  u += 0x7fffu + ((u >> 16) & 1u);   // RNE
  return (unsigned short)(u >> 16);
}

__device__ __forceinline__ f32x4 mfma16(s16x8 a, s16x8 b, f32x4 c) {
  return __builtin_amdgcn_mfma_f32_16x16x32_bf16(a, b, c, 0, 0, 0);
}

// ============ kernel 1: convert weights fp32 -> bf16 (Wq scaled) ============
__global__ __launch_bounds__(256) void wconv_k(const float* __restrict__ Wq,
                                               const float* __restrict__ Wk,
                                               const float* __restrict__ Wv,
                                               unsigned short* __restrict__ Wb) {
  int idx = (blockIdx.x * 256 + threadIdx.x) * 4;
  int tensor = idx >> 17;
  int r = idx & 131071;
  const float* src = tensor == 0 ? Wq : (tensor == 1 ? Wk : Wv);
  float4 f = *(const float4*)(src + r);
  float sc = (tensor == 0) ? QSCALE : 1.0f;
  ushort4 o;
  o.x = f2bf(f.x * sc); o.y = f2bf(f.y * sc);
  o.z = f2bf(f.z * sc); o.w = f2bf(f.w * sc);
  *(ushort4*)(Wb + idx) = o;
}

// ============ kernel 2: QKV projection GEMM (M=16384, N=384, K=1024) ========
// 512 blocks x 256 threads (4 waves), 32-row M-tiles. Wave wv owns n-tiles
// wv*6..wv*6+5. x staged via LDS (reg double-buffer); W B-frags direct from
// global (768KB, L2-resident, contiguous 16B loads).
__global__ __launch_bounds__(256, 2) void proj_k(const float* __restrict__ x,
    const float* __restrict__ bq, const float* __restrict__ bk,
    const float* __restrict__ bv, const unsigned short* __restrict__ Wb,
    unsigned short* __restrict__ Qg, unsigned short* __restrict__ Kg,
    unsigned short* __restrict__ Vtg) {
  __shared__ unsigned short smem[128 * 40];  // 10.2KB: xs[32][136] or vt[128][40]
  unsigned short* xs = smem;
  const int tid = threadIdx.x;
  const int wv = tid >> 6, ln = tid & 15, quad = (tid >> 4) & 3;
  const int mt = blockIdx.x;

  float bias[6];
  int tensor_[6], hcol_[6];
#pragma unroll
  for (int nt = 0; nt < 6; nt++) {
    int g_nt = wv * 6 + nt;
    int tensor = g_nt >> 3;
    int hcol = ((g_nt & 7) << 4) + ln;
    tensor_[nt] = tensor; hcol_[nt] = hcol;
    bias[nt] = (tensor == 0) ? bq[hcol] * QSCALE : (tensor == 1 ? bk[hcol] : bv[hcol]);
  }

  f32x4 acc[2][6];
  f32x4 zero = {0.f, 0.f, 0.f, 0.f};
#pragma unroll
  for (int m = 0; m < 2; m++)
#pragma unroll
    for (int nt = 0; nt < 6; nt++) acc[m][nt] = zero;

  float4 rX[4];
#define LOAD_X(KC)                                                             \
  _Pragma("unroll") for (int k = 0; k < 2; k++) {                              \
    int g = k * 256 + tid; int row = g >> 4, gc = g & 15;                      \
    const float* p = x + (size_t)(mt * 32 + row) * 1024 + (KC) * 128 + gc * 8; \
    rX[k * 2]     = *(const float4*)p;                                         \
    rX[k * 2 + 1] = *(const float4*)(p + 4);                                   \
  }
#define WRITE_X()                                                              \
  _Pragma("unroll") for (int k = 0; k < 2; k++) {                              \
    int g = k * 256 + tid; int row = g >> 4, gc = g & 15;                      \
    float4 f0 = rX[k * 2], f1 = rX[k * 2 + 1];                                 \
    u32x4 u;                                                                   \
    u.x = f2bf(f0.x) | ((unsigned)f2bf(f0.y) << 16);                           \
    u.y = f2bf(f0.z) | ((unsigned)f2bf(f0.w) << 16);                           \
    u.z = f2bf(f1.x) | ((unsigned)f2bf(f1.y) << 16);                           \
    u.w = f2bf(f1.z) | ((unsigned)f2bf(f1.w) << 16);                           \
    *(u32x4*)&xs[row * 136 + gc * 8] = u;                                      \
  }

  LOAD_X(0);
  for (int kc = 0; kc < 8; kc++) {
    WRITE_X();
    __syncthreads();
    if (kc < 7) { LOAD_X(kc + 1); }
#pragma unroll
    for (int ks = 0; ks < 4; ks++) {
      s16x8 a[2];
#pragma unroll
      for (int m = 0; m < 2; m++)
        a[m] = __builtin_bit_cast(s16x8,
            *(const u32x4*)&xs[(m * 16 + ln) * 136 + ks * 32 + quad * 8]);
#pragma unroll
      for (int nt = 0; nt < 6; nt++) {
        int nrow = (wv * 6 + nt) * 16 + ln;
        s16x8 b = __builtin_bit_cast(s16x8,
            *(const u32x4*)(Wb + (size_t)nrow * 1024 + kc * 128 + ks * 32 + quad * 8));
#pragma unroll
        for (int m = 0; m < 2; m++)
          acc[m][nt] = mfma16(a[m], b, acc[m][nt]);
      }
    }
    __syncthreads();
  }

  // epilogue: C-layout row = quad*4+reg, col = ln (m89-verified)
  const int r0 = mt * 32;
  const int batch = r0 >> 12, t0 = r0 & 4095;
  unsigned short* vt = smem;  // reuse as Vt tile [128 h][32 t + pad 8]
#pragma unroll
  for (int nt = 0; nt < 6; nt++) {
#pragma unroll
    for (int m = 0; m < 2; m++) {
#pragma unroll
      for (int reg = 0; reg < 4; reg++) {
        float val = acc[m][nt][reg] + bias[nt];
        unsigned short h = f2bf(val);
        int rl = m * 16 + quad * 4 + reg;
        if (tensor_[nt] == 0)      Qg[(size_t)(r0 + rl) * 128 + hcol_[nt]] = h;
        else if (tensor_[nt] == 1) Kg[(size_t)(r0 + rl) * 128 + hcol_[nt]] = h;
        else                       vt[hcol_[nt] * 40 + rl] = h;   // LDS transpose
      }
    }
  }
  __syncthreads();
  // coalesced copy-out: vt [128 h][32 t] -> Vtg[b][h][t]
#pragma unroll
  for (int k = 0; k < 2; k++) {
    int g = k * 256 + tid;            // 512 granules of 16B
    int h = g >> 2, gc = g & 3;
    u32x4 u = *(const u32x4*)&vt[h * 40 + gc * 8];
    *(u32x4*)((char*)Vtg + (size_t)batch * 1048576 + (size_t)h * 8192 + t0 * 2 + gc * 16) = u;
  }
}

// ============ kernel 3: causal attention, no-max softmax, pipelined =========
// BM=128 (4 waves x 32 rows), BN=64, seg = 8 chunks (512 keys). Dense grid of
// 576 blocks (slot == blockIdx). Direct-global K/V fragments with software
// pipeline: consume K(c) -> issue V(c) -> prefetch K(c+1); exp2+P-LDS section
// covers the load latency. No barriers in the loop. Partials in bf16.
__global__ __launch_bounds__(256, 2) void attn_k(const unsigned short* __restrict__ Qg,
    const unsigned short* __restrict__ Kg, const unsigned short* __restrict__ Vtg,
    unsigned short* __restrict__ Po, float* __restrict__ Plr) {
  __shared__ unsigned short Pl[128 * 72];  // 18.4KB, wave-private 32-row slabs
  const int tid = threadIdx.x;
  const int wv = tid >> 6, ln = tid & 15, quad = (tid >> 4) & 3;
  const int id = blockIdx.x;               // dense slot, 0..575
  const int b = id / 144;
  int rem = id - b * 144;
  int a_ = 0;
  while (2 * (a_ + 1) * (a_ + 2) <= rem) a_++;       // <=7 scalar iters
  const int off = rem - 2 * a_ * (a_ + 1);
  const int qt = 4 * a_ + off / (a_ + 1);
  const int seg = off - (off / (a_ + 1)) * (a_ + 1);
  const int qbase = qt * 128;
  const int totch = 2 * qt + 2;
  const int nch = min(8, totch - seg * 8);
  const int needw = 2 * qt + 1 + (wv >> 1);          // per-wave causal need
  const int nchw = min(nch, needw - seg * 8);

  const char* Kbase = (const char*)Kg + (size_t)b * 1048576;   // [t][h], 256B rows
  const char* Vbase = (const char*)Vtg + (size_t)b * 1048576;  // [h][t], 8192B rows

  // Q fragments: 2 m-tiles, A-layout (m=ln, k=quad*8+j + 32*ks)
  u32x4 qf[2][4];
#pragma unroll
  for (int m = 0; m < 2; m++) {
    const int qrow = b * 4096 + qbase + wv * 32 + m * 16 + ln;
#pragma unroll
    for (int ks = 0; ks < 4; ks++)
      qf[m][ks] = *(const u32x4*)((const char*)Qg + (size_t)qrow * 256 + ks * 64 + quad * 16);
  }

  f32x4 o[2][8];
  f32x4 lacc[2];
  f32x4 zero = {0.f, 0.f, 0.f, 0.f};
#pragma unroll
  for (int m = 0; m < 2; m++) {
    lacc[m] = zero;
#pragma unroll
    for (int i = 0; i < 8; i++) o[m][i] = zero;
  }
  const s16x8 onesb = {0x3F80, 0x3F80, 0x3F80, 0x3F80, 0x3F80, 0x3F80, 0x3F80, 0x3F80};

  u32x4 kb[16], kn[16], vb[16];
#define LOADK(dst, T0)                                                         \
  _Pragma("unroll") for (int ks = 0; ks < 4; ks++)                             \
    _Pragma("unroll") for (int nt = 0; nt < 4; nt++)                           \
      dst[ks * 4 + nt] = *(const u32x4*)(Kbase                                 \
          + (size_t)((T0) + nt * 16 + ln) * 256 + ks * 64 + quad * 16);
#define LOADV(dst, T0)                                                         \
  _Pragma("unroll") for (int k2 = 0; k2 < 2; k2++)                             \
    _Pragma("unroll") for (int nh = 0; nh < 8; nh++)                           \
      dst[k2 * 8 + nh] = *(const u32x4*)(Vbase                                 \
          + (size_t)(nh * 16 + ln) * 8192 + (T0) * 2 + k2 * 64 + quad * 16);

  LOADK(kb, seg * 512);
  for (int ci = 0; ci < nchw; ci++) {
    const int t0 = (seg * 8 + ci) * 64;

    // S = Q K^T (log2 domain via QSCALE folding) — consumes kb
    f32x4 s[2][4];
#pragma unroll
    for (int m = 0; m < 2; m++)
#pragma unroll
      for (int nt = 0; nt < 4; nt++) s[m][nt] = zero;
#pragma unroll
    for (int ks = 0; ks < 4; ks++)
#pragma unroll
      for (int nt = 0; nt < 4; nt++)
#pragma unroll
        for (int m = 0; m < 2; m++)
          s[m][nt] = mfma16(__builtin_bit_cast(s16x8, qf[m][ks]),
                            __builtin_bit_cast(s16x8, kb[ks * 4 + nt]), s[m][nt]);

    // issue V(c) now; exp2/P section below covers its latency
    LOADV(vb, t0);
    // prefetch K(c+1); PV section + next-iter top covers its latency
    if (ci + 1 < nchw) { LOADK(kn, t0 + 64); }

    // causal mask (diagonal-touching chunks only)
    if (t0 + 63 > qbase + wv * 32) {
#pragma unroll
      for (int m = 0; m < 2; m++)
#pragma unroll
        for (int nt = 0; nt < 4; nt++)
#pragma unroll
          for (int reg = 0; reg < 4; reg++) {
            int kidx = t0 + nt * 16 + ln;
            int qidx = qbase + wv * 32 + m * 16 + quad * 4 + reg;
            if (kidx > qidx) s[m][nt][reg] = -1e30f;
          }
    }

    // p = exp2(s), absolute domain -> bf16 -> wave-private LDS (C->A layout)
#pragma unroll
    for (int m = 0; m < 2; m++)
#pragma unroll
      for (int nt = 0; nt < 4; nt++)
#pragma unroll
        for (int reg = 0; reg < 4; reg++) {
          float pv = __builtin_amdgcn_exp2f(s[m][nt][reg]);
          Pl[(wv * 32 + m * 16 + quad * 4 + reg) * 72 + nt * 16 + ln] = f2bf(pv);
        }

    // PV + l accumulation (ones-B MFMA)
#pragma unroll
    for (int ks2 = 0; ks2 < 2; ks2++) {
      s16x8 pa[2];
#pragma unroll
      for (int m = 0; m < 2; m++)
        pa[m] = __builtin_bit_cast(s16x8,
            *(const u32x4*)&Pl[(wv * 32 + m * 16 + ln) * 72 + ks2 * 32 + quad * 8]);
#pragma unroll
      for (int nh = 0; nh < 8; nh++) {
        s16x8 vbf = __builtin_bit_cast(s16x8, vb[ks2 * 8 + nh]);
#pragma unroll
        for (int m = 0; m < 2; m++)
          o[m][nh] = mfma16(pa[m], vbf, o[m][nh]);
      }
#pragma unroll
      for (int m = 0; m < 2; m++)
        lacc[m] = mfma16(pa[m], onesb, lacc[m]);
    }

#pragma unroll
    for (int i = 0; i < 16; i++) kb[i] = kn[i];
  }

  // epilogue: bf16 unnormalized partial + fp32 row sums
  unsigned short* po = Po + (size_t)id * 16384;
#pragma unroll
  for (int m = 0; m < 2; m++) {
#pragma unroll
    for (int reg = 0; reg < 4; reg++) {
      int rowl = wv * 32 + m * 16 + quad * 4 + reg;
#pragma unroll
      for (int nh = 0; nh < 8; nh++)
        po[rowl * 128 + nh * 16 + ln] = f2bf(o[m][nh][reg]);
      if (ln == 0) Plr[id * 128 + rowl] = lacc[m][reg];
    }
  }
}

// ============ kernel 4: combine bf16 partials (pure sums, coalesced) ========
// 512 blocks: tile (b,qt) split in 4 quarters; thread handles 2 granules of
// 8 bf16 elems; fully dense 256B-per-4-lane access pattern.
__global__ __launch_bounds__(256) void combine_k(const unsigned short* __restrict__ Po,
    const float* __restrict__ Plr, float* __restrict__ out) {
  const int id = blockIdx.x;
  const int tileid = id >> 2, quarter = id & 3;
  const int qt = tileid & 31;
  const int b = tileid >> 5;
  const int a_ = qt >> 2, r_ = qt & 3;
  const int base = b * 144 + 2 * a_ * (a_ + 1) + r_ * (a_ + 1);
  const int nseg = a_ + 1;
  const int tid = threadIdx.x;
#pragma unroll
  for (int i = 0; i < 2; i++) {
    int g = quarter * 512 + i * 256 + tid;   // granule of 8 elems; 2048/tile
    int row = g >> 4;
    float acc[8] = {0.f, 0.f, 0.f, 0.f, 0.f, 0.f, 0.f, 0.f};
    float L = 0.f;
    for (int s = 0; s < nseg; s++) {
      u32x4 u = *(const u32x4*)(Po + (size_t)(base + s) * 16384 + g * 8);
      L += Plr[(base + s) * 128 + row];
      acc[0] += __builtin_bit_cast(float, u.x << 16);
      acc[1] += __builtin_bit_cast(float, u.x & 0xffff0000u);
      acc[2] += __builtin_bit_cast(float, u.y << 16);
      acc[3] += __builtin_bit_cast(float, u.y & 0xffff0000u);
      acc[4] += __builtin_bit_cast(float, u.z << 16);
      acc[5] += __builtin_bit_cast(float, u.z & 0xffff0000u);
      acc[6] += __builtin_bit_cast(float, u.w << 16);
      acc[7] += __builtin_bit_cast(float, u.w & 0xffff0000u);
    }
    float inv = 1.f / L;
    float* op = out + (size_t)tileid * 16384 + g * 8;
    f32x4 o0 = {acc[0] * inv, acc[1] * inv, acc[2] * inv, acc[3] * inv};
    f32x4 o1 = {acc[4] * inv, acc[5] * inv, acc[6] * inv, acc[7] * inv};
    *(f32x4*)op = o0;
    *(f32x4*)(op + 4) = o1;
  }
}

// ============ launch ============
extern "C" void kernel_launch(void* const* d_in, const int* in_sizes, int n_in,
                              void* d_out, int out_size, void* d_ws, size_t ws_size,
                              hipStream_t stream) {
  const float* x  = (const float*)d_in[0];
  const float* Wq = (const float*)d_in[1];
  const float* bq = (const float*)d_in[2];
  const float* Wk = (const float*)d_in[3];
  const float* bk = (const float*)d_in[4];
  const float* Wv = (const float*)d_in[5];
  const float* bv = (const float*)d_in[6];
  float* out = (float*)d_out;

  char* wsb = (char*)d_ws;
  unsigned short* Wb  = (unsigned short*)wsb;                 // 768 KB
  unsigned short* Qg  = (unsigned short*)(wsb + 786432);      // 4 MB
  unsigned short* Kg  = (unsigned short*)(wsb + 4980736);     // 4 MB
  unsigned short* Vtg = (unsigned short*)(wsb + 9175040);     // 4 MB
  unsigned short* Po  = (unsigned short*)(wsb + 13369344);    // 18.9 MB (576 slots, bf16)
  float* Plr = (float*)(wsb + 32243712);                      // 288 KB

  wconv_k<<<dim3(384), dim3(256), 0, stream>>>(Wq, Wk, Wv, Wb);
  proj_k<<<dim3(512), dim3(256), 0, stream>>>(x, bq, bk, bv, Wb, Qg, Kg, Vtg);
  attn_k<<<dim3(576), dim3(256), 0, stream>>>(Qg, Kg, Vtg, Po, Plr);
  combine_k<<<dim3(512), dim3(256), 0, stream>>>(Po, Plr, out);
}

// Round 6
// 240.709 us; speedup vs baseline: 1.2963x; 1.2963x over previous
//
#include <hip/hip_runtime.h>
#include <stdint.h>

// ---- types ----
typedef short s16x8 __attribute__((ext_vector_type(8)));
typedef float f32x4 __attribute__((ext_vector_type(4)));
typedef unsigned int u32x4 __attribute__((ext_vector_type(4)));

// log2(e) / sqrt(128): fold softmax scale + exp2 conversion into Q projection
#define QSCALE 0.12751743f

__device__ __forceinline__ unsigned short f2bf(float f) {
  unsigned int u = __builtin_bit_cast(unsigned int, f);
  u += 0x7fffu + ((u >> 16) & 1u);   // RNE
  return (unsigned short)(u >> 16);
}

__device__ __forceinline__ f32x4 mfma16(s16x8 a, s16x8 b, f32x4 c) {
  return __builtin_amdgcn_mfma_f32_16x16x32_bf16(a, b, c, 0, 0, 0);
}

// async global->LDS DMA, 16B/lane, dest = wave-uniform base + lane*16
#define GLD(GP, LP)                                                            \
  __builtin_amdgcn_global_load_lds(                                            \
      (const __attribute__((address_space(1))) unsigned int*)(GP),             \
      (__attribute__((address_space(3))) unsigned int*)(LP), 16, 0, 0)

// ============ kernel 1: convert weights fp32 -> bf16 (Wq scaled) ============
__global__ __launch_bounds__(256) void wconv_k(const float* __restrict__ Wq,
                                               const float* __restrict__ Wk,
                                               const float* __restrict__ Wv,
                                               unsigned short* __restrict__ Wb) {
  int idx = (blockIdx.x * 256 + threadIdx.x) * 4;
  int tensor = idx >> 17;
  int r = idx & 131071;
  const float* src = tensor == 0 ? Wq : (tensor == 1 ? Wk : Wv);
  float4 f = *(const float4*)(src + r);
  float sc = (tensor == 0) ? QSCALE : 1.0f;
  ushort4 o;
  o.x = f2bf(f.x * sc); o.y = f2bf(f.y * sc);
  o.z = f2bf(f.z * sc); o.w = f2bf(f.w * sc);
  *(ushort4*)(Wb + idx) = o;
}

// ============ kernel 2: QKV projection GEMM (M=16384, N=384, K=1024) ========
// 1024 blocks x 256 threads (4 waves), 16-row M-tiles. Wave wv owns n-tiles
// wv*6..wv*6+5. x chunk (16x64 fp32 = 4KB) DMA'd into LDS (double-buffered,
// zero VGPR cost), converted to bf16 at fragment build. W B-frags direct from
// global (768KB, L2-resident). One barrier per K-chunk.
__global__ __launch_bounds__(256, 4) void proj_k(const float* __restrict__ x,
    const float* __restrict__ bq, const float* __restrict__ bk,
    const float* __restrict__ bv, const unsigned short* __restrict__ Wb,
    unsigned short* __restrict__ Qg, unsigned short* __restrict__ Kg,
    unsigned short* __restrict__ Vtg) {
  __shared__ unsigned int xbuf[2][1024];     // 2 x 4KB, col-granule-major
  __shared__ unsigned short vt[128 * 24];    // 6KB epilogue transpose
  const int tid = threadIdx.x;
  const int wv = tid >> 6, ln = tid & 15, quad = (tid >> 4) & 3;
  const int mt = blockIdx.x;

  float bias[6];
  int tensor_[6], hcol_[6];
#pragma unroll
  for (int nt = 0; nt < 6; nt++) {
    int g_nt = wv * 6 + nt;
    int tensor = g_nt >> 3;
    int hcol = ((g_nt & 7) << 4) + ln;
    tensor_[nt] = tensor; hcol_[nt] = hcol;
    bias[nt] = (tensor == 0) ? bq[hcol] * QSCALE : (tensor == 1 ? bk[hcol] : bv[hcol]);
  }

  f32x4 acc[6];
  f32x4 zero = {0.f, 0.f, 0.f, 0.f};
#pragma unroll
  for (int nt = 0; nt < 6; nt++) acc[nt] = zero;

  // x DMA: granule idx = c*16 + r == tid (c = tid>>4, r = tid&15); wave wv
  // issues instruction covering granules [wv*64, wv*64+64).
#define PJ_DMA(BUF, KC)                                                        \
  GLD(x + (size_t)(mt * 16 + (tid & 15)) * 1024 + (KC) * 64 + (tid >> 4) * 4,  \
      &xbuf[BUF][(tid >> 6) * 256]);

  PJ_DMA(0, 0);
  for (int kc = 0; kc < 16; kc++) {
    const int cur = kc & 1;
    __syncthreads();                 // DMA(cur) complete; prior reads done
    if (kc + 1 < 16) { PJ_DMA(cur ^ 1, kc + 1); }
#pragma unroll
    for (int ks = 0; ks < 2; ks++) {
      // A-frag: x[m=ln][k = ks*32 + quad*8 + j] from fp32 granules
      f32x4 lo = *(const f32x4*)&xbuf[cur][(((ks * 8 + quad * 2)) * 16 + ln) * 4];
      f32x4 hi = *(const f32x4*)&xbuf[cur][(((ks * 8 + quad * 2 + 1)) * 16 + ln) * 4];
      u32x4 af;
      af.x = f2bf(lo.x) | ((unsigned)f2bf(lo.y) << 16);
      af.y = f2bf(lo.z) | ((unsigned)f2bf(lo.w) << 16);
      af.z = f2bf(hi.x) | ((unsigned)f2bf(hi.y) << 16);
      af.w = f2bf(hi.z) | ((unsigned)f2bf(hi.w) << 16);
      s16x8 a = __builtin_bit_cast(s16x8, af);
#pragma unroll
      for (int nt = 0; nt < 6; nt++) {
        int nrow = (wv * 6 + nt) * 16 + ln;
        s16x8 b = __builtin_bit_cast(s16x8,
            *(const u32x4*)(Wb + (size_t)nrow * 1024 + kc * 64 + ks * 32 + quad * 8));
        acc[nt] = mfma16(a, b, acc[nt]);
      }
    }
  }

  // epilogue: C-layout row = quad*4+reg, col = ln (m89-verified)
  const int r0 = mt * 16;
  const int batch = r0 >> 12, t0 = r0 & 4095;
  __syncthreads();
#pragma unroll
  for (int nt = 0; nt < 6; nt++) {
#pragma unroll
    for (int reg = 0; reg < 4; reg++) {
      float val = acc[nt][reg] + bias[nt];
      unsigned short h = f2bf(val);
      int rl = quad * 4 + reg;
      if (tensor_[nt] == 0)      Qg[(size_t)(r0 + rl) * 128 + hcol_[nt]] = h;
      else if (tensor_[nt] == 1) Kg[(size_t)(r0 + rl) * 128 + hcol_[nt]] = h;
      else                       vt[hcol_[nt] * 24 + rl] = h;   // LDS transpose
    }
  }
  __syncthreads();
  // coalesced copy-out: vt [128 h][16 t] -> Vtg[b][h][t]; 256 granules
  {
    int h = tid >> 1, gc = tid & 1;
    u32x4 u = *(const u32x4*)&vt[h * 24 + gc * 8];
    *(u32x4*)((char*)Vtg + (size_t)batch * 1048576 + (size_t)h * 8192 + t0 * 2 + gc * 16) = u;
  }
}

// ============ kernel 3: causal attention, DMA-pipelined, no-max softmax =====
// BM=128 (4 waves x 32 rows), BN=32, seg = 16 chunks (512 keys), dense grid of
// 576 blocks. K/V chunks DMA'd into double-buffered LDS (col-granule-major:
// fragment-read bank index == ln mod 8 -> 2-way, free). One barrier per chunk.
// p = exp2(s) absolute domain; l via ones-B MFMA; bf16 partials.
__global__ __launch_bounds__(256, 3) void attn_k(const unsigned short* __restrict__ Qg,
    const unsigned short* __restrict__ Kg, const unsigned short* __restrict__ Vtg,
    unsigned short* __restrict__ Po, float* __restrict__ Plr) {
  __shared__ unsigned int ldsK[2][2048];   // 2 x 8KB: K chunk [32 t][128 h]
  __shared__ unsigned int ldsV[2][2048];   // 2 x 8KB: Vt chunk [128 h][32 t]
  __shared__ unsigned short Pl[128 * 40];  // 10.2KB (stride 40: A-read 2-way free)
  const int tid = threadIdx.x;
  const int wv = tid >> 6, ln = tid & 15, quad = (tid >> 4) & 3;
  const int lane = tid & 63;
  const int id = blockIdx.x;               // dense slot, 0..575
  const int b = id / 144;
  int rem = id - b * 144;
  int a_ = 0;
  while (2 * (a_ + 1) * (a_ + 2) <= rem) a_++;       // <=7 scalar iters
  const int off = rem - 2 * a_ * (a_ + 1);
  const int qt = 4 * a_ + off / (a_ + 1);
  const int seg = off - (off / (a_ + 1)) * (a_ + 1);
  const int qbase = qt * 128;
  const int totch = 4 * qt + 4;                      // 32-key chunks for tile
  const int nch = min(16, totch - seg * 16);

  const char* Kbase = (const char*)Kg + (size_t)b * 1048576;   // [t][h], 256B rows
  const char* Vbase = (const char*)Vtg + (size_t)b * 1048576;  // [h][t], 8192B rows

  // Q fragments: 2 m-tiles, A-layout (m=ln, k=quad*8+j + 32*ks)
  u32x4 qf[2][4];
#pragma unroll
  for (int m = 0; m < 2; m++) {
    const int qrow = b * 4096 + qbase + wv * 32 + m * 16 + ln;
#pragma unroll
    for (int ks = 0; ks < 4; ks++)
      qf[m][ks] = *(const u32x4*)((const char*)Qg + (size_t)qrow * 256 + ks * 64 + quad * 16);
  }

  f32x4 o[2][8];
  f32x4 lacc[2];
  f32x4 zero = {0.f, 0.f, 0.f, 0.f};
#pragma unroll
  for (int m = 0; m < 2; m++) {
    lacc[m] = zero;
#pragma unroll
    for (int i = 0; i < 8; i++) o[m][i] = zero;
  }
  const s16x8 onesb = {0x3F80, 0x3F80, 0x3F80, 0x3F80, 0x3F80, 0x3F80, 0x3F80, 0x3F80};

  // DMA one 32-key chunk: 8 K-instr + 8 V-instr, wave wv issues j=2wv,2wv+1.
  // K layout: granule (r=t,c) at idx c*32+r (c in [0,16)). V: (r=h,c) at
  // idx c*128+r (c in [0,4)).
#define ATTN_DMA(BUF, T0)                                                      \
  _Pragma("unroll") for (int jj = 0; jj < 2; jj++) {                           \
    int j = wv * 2 + jj;                                                       \
    int g = j * 64 + lane;                                                     \
    GLD(Kbase + (size_t)((T0) + (g & 31)) * 256 + (g >> 5) * 16,               \
        &ldsK[BUF][j * 256]);                                                  \
    GLD(Vbase + (size_t)((j & 1) * 64 + lane) * 8192 + (size_t)(T0) * 2        \
            + (j >> 1) * 16,                                                   \
        &ldsV[BUF][j * 256]);                                                  \
  }

  ATTN_DMA(0, seg * 512);
  for (int ci = 0; ci < nch; ci++) {
    const int cur = ci & 1;
    const int t0 = (seg * 16 + ci) * 32;
    __syncthreads();                 // DMA(cur) visible; prior reads of cur done
    if (ci + 1 < nch) { ATTN_DMA(cur ^ 1, t0 + 32); }

    // S = Q K^T (log2 domain via QSCALE folding)
    f32x4 s[2][2];
#pragma unroll
    for (int m = 0; m < 2; m++)
#pragma unroll
      for (int nt = 0; nt < 2; nt++) s[m][nt] = zero;
#pragma unroll
    for (int ks = 0; ks < 4; ks++)
#pragma unroll
      for (int nt = 0; nt < 2; nt++) {
        s16x8 kf = __builtin_bit_cast(s16x8,
            *(const u32x4*)&ldsK[cur][((ks * 4 + quad) * 32 + nt * 16 + ln) * 4]);
#pragma unroll
        for (int m = 0; m < 2; m++)
          s[m][nt] = mfma16(__builtin_bit_cast(s16x8, qf[m][ks]), kf, s[m][nt]);
      }

    // causal mask (diagonal-touching chunks; fully-masked tail chunks -> p=0)
    if (t0 + 31 > qbase + wv * 32) {
#pragma unroll
      for (int m = 0; m < 2; m++)
#pragma unroll
        for (int nt = 0; nt < 2; nt++)
#pragma unroll
          for (int reg = 0; reg < 4; reg++) {
            int kidx = t0 + nt * 16 + ln;
            int qidx = qbase + wv * 32 + m * 16 + quad * 4 + reg;
            if (kidx > qidx) s[m][nt][reg] = -1e30f;
          }
    }

    // p = exp2(s) -> bf16 -> wave-private LDS (C->A layout round-trip)
#pragma unroll
    for (int m = 0; m < 2; m++)
#pragma unroll
      for (int nt = 0; nt < 2; nt++)
#pragma unroll
        for (int reg = 0; reg < 4; reg++) {
          float pv = __builtin_amdgcn_exp2f(s[m][nt][reg]);
          Pl[(wv * 32 + m * 16 + quad * 4 + reg) * 40 + nt * 16 + ln] = f2bf(pv);
        }

    // PV + l accumulation (K-dim = 32 -> single A-frag per m)
    s16x8 pa[2];
#pragma unroll
    for (int m = 0; m < 2; m++)
      pa[m] = __builtin_bit_cast(s16x8,
          *(const u32x4*)&Pl[(wv * 32 + m * 16 + ln) * 40 + quad * 8]);
#pragma unroll
    for (int nh = 0; nh < 8; nh++) {
      s16x8 vf = __builtin_bit_cast(s16x8,
          *(const u32x4*)&ldsV[cur][(quad * 128 + nh * 16 + ln) * 4]);
#pragma unroll
      for (int m = 0; m < 2; m++)
        o[m][nh] = mfma16(pa[m], vf, o[m][nh]);
    }
#pragma unroll
    for (int m = 0; m < 2; m++)
      lacc[m] = mfma16(pa[m], onesb, lacc[m]);
  }

  // epilogue: bf16 unnormalized partial + fp32 row sums
  unsigned short* po = Po + (size_t)id * 16384;
#pragma unroll
  for (int m = 0; m < 2; m++) {
#pragma unroll
    for (int reg = 0; reg < 4; reg++) {
      int rowl = wv * 32 + m * 16 + quad * 4 + reg;
#pragma unroll
      for (int nh = 0; nh < 8; nh++)
        po[rowl * 128 + nh * 16 + ln] = f2bf(o[m][nh][reg]);
      if (ln == 0) Plr[id * 128 + rowl] = lacc[m][reg];
    }
  }
}

// ============ kernel 4: combine bf16 partials (pure sums, coalesced) ========
__global__ __launch_bounds__(256) void combine_k(const unsigned short* __restrict__ Po,
    const float* __restrict__ Plr, float* __restrict__ out) {
  const int id = blockIdx.x;
  const int tileid = id >> 2, quarter = id & 3;
  const int qt = tileid & 31;
  const int b = tileid >> 5;
  const int a_ = qt >> 2, r_ = qt & 3;
  const int base = b * 144 + 2 * a_ * (a_ + 1) + r_ * (a_ + 1);
  const int nseg = a_ + 1;
  const int tid = threadIdx.x;
#pragma unroll
  for (int i = 0; i < 2; i++) {
    int g = quarter * 512 + i * 256 + tid;   // granule of 8 elems; 2048/tile
    int row = g >> 4;
    float acc[8] = {0.f, 0.f, 0.f, 0.f, 0.f, 0.f, 0.f, 0.f};
    float L = 0.f;
    for (int s = 0; s < nseg; s++) {
      u32x4 u = *(const u32x4*)(Po + (size_t)(base + s) * 16384 + g * 8);
      L += Plr[(base + s) * 128 + row];
      acc[0] += __builtin_bit_cast(float, u.x << 16);
      acc[1] += __builtin_bit_cast(float, u.x & 0xffff0000u);
      acc[2] += __builtin_bit_cast(float, u.y << 16);
      acc[3] += __builtin_bit_cast(float, u.y & 0xffff0000u);
      acc[4] += __builtin_bit_cast(float, u.z << 16);
      acc[5] += __builtin_bit_cast(float, u.z & 0xffff0000u);
      acc[6] += __builtin_bit_cast(float, u.w << 16);
      acc[7] += __builtin_bit_cast(float, u.w & 0xffff0000u);
    }
    float inv = 1.f / L;
    float* op = out + (size_t)tileid * 16384 + g * 8;
    f32x4 o0 = {acc[0] * inv, acc[1] * inv, acc[2] * inv, acc[3] * inv};
    f32x4 o1 = {acc[4] * inv, acc[5] * inv, acc[6] * inv, acc[7] * inv};
    *(f32x4*)op = o0;
    *(f32x4*)(op + 4) = o1;
  }
}

// ============ launch ============
extern "C" void kernel_launch(void* const* d_in, const int* in_sizes, int n_in,
                              void* d_out, int out_size, void* d_ws, size_t ws_size,
                              hipStream_t stream) {
  const float* x  = (const float*)d_in[0];
  const float* Wq = (const float*)d_in[1];
  const float* bq = (const float*)d_in[2];
  const float* Wk = (const float*)d_in[3];
  const float* bk = (const float*)d_in[4];
  const float* Wv = (const float*)d_in[5];
  const float* bv = (const float*)d_in[6];
  float* out = (float*)d_out;

  char* wsb = (char*)d_ws;
  unsigned short* Wb  = (unsigned short*)wsb;                 // 768 KB
  unsigned short* Qg  = (unsigned short*)(wsb + 786432);      // 4 MB
  unsigned short* Kg  = (unsigned short*)(wsb + 4980736);     // 4 MB
  unsigned short* Vtg = (unsigned short*)(wsb + 9175040);     // 4 MB
  unsigned short* Po  = (unsigned short*)(wsb + 13369344);    // 18.9 MB (576 slots, bf16)
  float* Plr = (float*)(wsb + 32243712);                      // 288 KB

  wconv_k<<<dim3(384), dim3(256), 0, stream>>>(Wq, Wk, Wv, Wb);
  proj_k<<<dim3(1024), dim3(256), 0, stream>>>(x, bq, bk, bv, Wb, Qg, Kg, Vtg);
  attn_k<<<dim3(576), dim3(256), 0, stream>>>(Qg, Kg, Vtg, Po, Plr);
  combine_k<<<dim3(512), dim3(256), 0, stream>>>(Po, Plr, out);
}

// Round 7
// 187.090 us; speedup vs baseline: 1.6679x; 1.2866x over previous
//
#include <hip/hip_runtime.h>
#include <stdint.h>

// ---- types ----
typedef short s16x8 __attribute__((ext_vector_type(8)));
typedef float f32x4 __attribute__((ext_vector_type(4)));
typedef unsigned int u32x4 __attribute__((ext_vector_type(4)));

// log2(e) / sqrt(128): fold softmax scale + exp2 conversion into Q projection
#define QSCALE 0.12751743f

__device__ __forceinline__ unsigned short f2bf(float f) {
  unsigned int u = __builtin_bit_cast(unsigned int, f);
  u += 0x7fffu + ((u >> 16) & 1u);   // RNE
  return (unsigned short)(u >> 16);
}

__device__ __forceinline__ f32x4 mfma16(s16x8 a, s16x8 b, f32x4 c) {
  return __builtin_amdgcn_mfma_f32_16x16x32_bf16(a, b, c, 0, 0, 0);
}

// async global->LDS DMA, 16B/lane, dest = wave-uniform base + lane*16
#define GLD(GP, LP)                                                            \
  __builtin_amdgcn_global_load_lds(                                            \
      (const __attribute__((address_space(1))) unsigned int*)(GP),             \
      (__attribute__((address_space(3))) unsigned int*)(LP), 16, 0, 0)

// ============ kernel 1: weights fp32 -> bf16, K-chunk-tiled + swizzled ======
// Wt layout: [kc(32k)][n(384)][4 granules, col = gk ^ ((n>>1)&3)][8 elems]
__global__ __launch_bounds__(256) void wconv_k(const float* __restrict__ Wq,
                                               const float* __restrict__ Wk,
                                               const float* __restrict__ Wv,
                                               unsigned short* __restrict__ Wt) {
  int idx = (blockIdx.x * 256 + threadIdx.x) * 4;   // 393216 elems
  int tensor = idx >> 17;
  int r = idx & 131071;
  const float* src = tensor == 0 ? Wq : (tensor == 1 ? Wk : Wv);
  float4 f = *(const float4*)(src + r);
  float sc = (tensor == 0) ? QSCALE : 1.0f;
  ushort4 o;
  o.x = f2bf(f.x * sc); o.y = f2bf(f.y * sc);
  o.z = f2bf(f.z * sc); o.w = f2bf(f.w * sc);
  int nl = r >> 10, k = r & 1023;
  int n = tensor * 128 + nl;
  int kc = k >> 5, kl = k & 31, gk = kl >> 3, j = kl & 7;  // j in {0,4}
  int gks = gk ^ ((n >> 1) & 3);
  *(ushort4*)(Wt + kc * 12288 + (n * 4 + gks) * 8 + j) = o;
}

// ============ kernel 2: QKV projection GEMM (M=16384, N=384, K=1024) ========
// 512 blocks x 256 threads (4 waves), 32-row tiles, BK=32. x and W both DMA'd
// into double-buffered LDS with swizzled layouts (conflict-free frag reads).
// Outputs: Qg row-major; K/V into per-32-key combined 16KB tiles (swizzled).
__global__ __launch_bounds__(256, 2) void proj_k(const float* __restrict__ x,
    const float* __restrict__ bq, const float* __restrict__ bk,
    const float* __restrict__ bv, const unsigned short* __restrict__ Wt,
    unsigned short* __restrict__ Qg, unsigned short* __restrict__ KVg) {
  __shared__ unsigned int xb[2][2048];       // 2 x 8KB: x chunk [32r][8 gx swz] fp32
  __shared__ unsigned short wb[2][12288];    // 2 x 24KB: W chunk [384n][4 gk swz]
  const int tid = threadIdx.x;
  const int wv = tid >> 6, ln = tid & 15, quad = (tid >> 4) & 3;
  const int lane = tid & 63;
  const int mt = blockIdx.x;

  float bias[6];
  int tensor_[6], hcol_[6];
#pragma unroll
  for (int nt = 0; nt < 6; nt++) {
    int g_nt = wv * 6 + nt;
    int tensor = g_nt >> 3;
    int hcol = ((g_nt & 7) << 4) + ln;
    tensor_[nt] = tensor; hcol_[nt] = hcol;
    bias[nt] = (tensor == 0) ? bq[hcol] * QSCALE : (tensor == 1 ? bk[hcol] : bv[hcol]);
  }

  f32x4 acc[2][6];
  f32x4 zero = {0.f, 0.f, 0.f, 0.f};
#pragma unroll
  for (int m = 0; m < 2; m++)
#pragma unroll
    for (int nt = 0; nt < 6; nt++) acc[m][nt] = zero;

  // x DMA: lane covers granule idx = wv*64+lane; LDS slot idx, global granule
  // gx = (idx&7) ^ (row&7) within row's 128B window (swizzle baked at load).
  // W DMA: 6 contiguous 1KB instrs/wave (global already swizzled).
#define PJ_DMA(BUF, KC)                                                        \
  {                                                                            \
    int idx = wv * 64 + lane;                                                  \
    int r_ = idx >> 3, gx = (idx & 7) ^ (r_ & 7);                              \
    GLD(x + (size_t)(mt * 32 + r_) * 1024 + (KC) * 32 + gx * 4,                \
        &xb[BUF][wv * 256]);                                                   \
  }                                                                            \
  _Pragma("unroll") for (int i = 0; i < 6; i++) {                              \
    GLD(Wt + (size_t)(KC) * 12288 + ((wv * 6 + i) * 64 + lane) * 8,            \
        &wb[BUF][(wv * 6 + i) * 512]);                                         \
  }

  PJ_DMA(0, 0);
  for (int kc = 0; kc < 32; kc++) {
    const int cur = kc & 1;
    __syncthreads();                 // DMA(cur) complete; prior reads done
    if (kc + 1 < 32) { PJ_DMA(cur ^ 1, kc + 1); }

    s16x8 a[2];
#pragma unroll
    for (int m = 0; m < 2; m++) {
      int r_ = m * 16 + ln;
      int c0 = (quad * 2) ^ (r_ & 7);
      int c1 = c0 ^ 1;
      f32x4 lo = *(const f32x4*)&xb[cur][(r_ * 8 + c0) * 4];
      f32x4 hi = *(const f32x4*)&xb[cur][(r_ * 8 + c1) * 4];
      u32x4 af;
      af.x = f2bf(lo.x) | ((unsigned)f2bf(lo.y) << 16);
      af.y = f2bf(lo.z) | ((unsigned)f2bf(lo.w) << 16);
      af.z = f2bf(hi.x) | ((unsigned)f2bf(hi.y) << 16);
      af.w = f2bf(hi.z) | ((unsigned)f2bf(hi.w) << 16);
      a[m] = __builtin_bit_cast(s16x8, af);
    }
#pragma unroll
    for (int nt = 0; nt < 6; nt++) {
      int n = (wv * 6 + nt) * 16 + ln;
      int gks = quad ^ ((n >> 1) & 3);
      s16x8 b = __builtin_bit_cast(s16x8, *(const u32x4*)&wb[cur][(n * 4 + gks) * 8]);
#pragma unroll
      for (int m = 0; m < 2; m++)
        acc[m][nt] = mfma16(a[m], b, acc[m][nt]);
    }
  }

  // epilogue: C-layout row = quad*4+reg, col = ln (m89-verified).
  // K tile elem (tr,h): (tr*16 + ghs)*8 + (h&7), ghs = (gh&8)|((gh&7)^(tr&7))
  // V tile elem (tr,h): 4096 + (h*4 + gts)*8 + (tr&7), gts = (tr>>3)^((h>>1)&3)
  const int r0 = mt * 32;
#pragma unroll
  for (int nt = 0; nt < 6; nt++) {
    int hcol = hcol_[nt];
#pragma unroll
    for (int m = 0; m < 2; m++) {
#pragma unroll
      for (int reg = 0; reg < 4; reg++) {
        float val = acc[m][nt][reg] + bias[nt];
        unsigned short h = f2bf(val);
        int rl = m * 16 + quad * 4 + reg;       // 0..31 == tr (32-row tiles)
        int t_abs = r0 + rl;
        size_t chbase = (size_t)((t_abs >> 12) * 128 + ((t_abs & 4095) >> 5)) * 8192;
        if (tensor_[nt] == 0) {
          Qg[(size_t)t_abs * 128 + hcol] = h;
        } else if (tensor_[nt] == 1) {
          int gh = hcol >> 3;
          int ghs = (gh & 8) | ((gh & 7) ^ (rl & 7));
          KVg[chbase + (rl * 16 + ghs) * 8 + (hcol & 7)] = h;
        } else {
          int gts = (rl >> 3) ^ ((hcol >> 1) & 3);
          KVg[chbase + 4096 + (hcol * 4 + gts) * 8 + (rl & 7)] = h;
        }
      }
    }
  }
}

// ============ kernel 3: causal attention, DMA-pipelined, no-max softmax =====
// BM=128 (4 waves x 32 rows), BN=32, seg=16 chunks, dense 576-block grid.
// Per chunk: one 16KB combined K/V tile DMA'd linearly (4 x 1KB per wave) into
// dbuf LDS; swizzled layouts give conflict-free b128 fragment reads. One
// barrier per chunk. p = exp2(s); l via ones-B MFMA; bf16 partials.
__global__ __launch_bounds__(256, 3) void attn_k(const unsigned short* __restrict__ Qg,
    const unsigned short* __restrict__ KVg,
    unsigned short* __restrict__ Po, float* __restrict__ Plr) {
  __shared__ unsigned short kvb[2][8192];  // 2 x 16KB (K tile 8KB | V tile 8KB)
  __shared__ unsigned short Pl[128 * 40];  // 10KB, wave-private rows
  const int tid = threadIdx.x;
  const int wv = tid >> 6, ln = tid & 15, quad = (tid >> 4) & 3;
  const int lane = tid & 63;
  const int id = blockIdx.x;               // dense slot, 0..575
  const int b = id / 144;
  int rem = id - b * 144;
  int a_ = 0;
  while (2 * (a_ + 1) * (a_ + 2) <= rem) a_++;       // <=7 scalar iters
  const int off = rem - 2 * a_ * (a_ + 1);
  const int qt = 4 * a_ + off / (a_ + 1);
  const int seg = off - (off / (a_ + 1)) * (a_ + 1);
  const int qbase = qt * 128;
  const int totch = 4 * qt + 4;
  const int nch = min(16, totch - seg * 16);

  const unsigned short* KVb = KVg + (size_t)b * 1048576;  // 128 chunks x 8192 elems

  // Q fragments: 2 m-tiles, A-layout (m=ln, k=quad*8+j + 32*ks)
  u32x4 qf[2][4];
#pragma unroll
  for (int m = 0; m < 2; m++) {
    const int qrow = b * 4096 + qbase + wv * 32 + m * 16 + ln;
#pragma unroll
    for (int ks = 0; ks < 4; ks++)
      qf[m][ks] = *(const u32x4*)((const char*)Qg + (size_t)qrow * 256 + ks * 64 + quad * 16);
  }

  f32x4 o[2][8];
  f32x4 lacc[2];
  f32x4 zero = {0.f, 0.f, 0.f, 0.f};
#pragma unroll
  for (int m = 0; m < 2; m++) {
    lacc[m] = zero;
#pragma unroll
    for (int i = 0; i < 8; i++) o[m][i] = zero;
  }
  const s16x8 onesb = {0x3F80, 0x3F80, 0x3F80, 0x3F80, 0x3F80, 0x3F80, 0x3F80, 0x3F80};

#define ATTN_DMA(BUF, CH)                                                      \
  _Pragma("unroll") for (int i = 0; i < 4; i++) {                              \
    GLD(KVb + (size_t)(CH) * 8192 + (wv * 4 + i) * 512 + lane * 8,             \
        &kvb[BUF][(wv * 4 + i) * 512]);                                        \
  }

  ATTN_DMA(0, seg * 16);
  for (int ci = 0; ci < nch; ci++) {
    const int cur = ci & 1;
    const int ch = seg * 16 + ci;
    const int t0 = ch * 32;
    __syncthreads();                 // DMA(cur) visible; prior reads of cur done
    if (ci + 1 < nch) { ATTN_DMA(cur ^ 1, ch + 1); }

    // S = Q K^T; K frag (t = nt*16+ln, granule gh = ks*4+quad, swizzled)
    f32x4 s[2][2];
#pragma unroll
    for (int m = 0; m < 2; m++)
#pragma unroll
      for (int nt = 0; nt < 2; nt++) s[m][nt] = zero;
#pragma unroll
    for (int ks = 0; ks < 4; ks++)
#pragma unroll
      for (int nt = 0; nt < 2; nt++) {
        int t = nt * 16 + ln;
        int gh = ks * 4 + quad;
        int ghs = (gh & 8) | ((gh & 7) ^ (t & 7));
        s16x8 kf = __builtin_bit_cast(s16x8, *(const u32x4*)&kvb[cur][(t * 16 + ghs) * 8]);
#pragma unroll
        for (int m = 0; m < 2; m++)
          s[m][nt] = mfma16(__builtin_bit_cast(s16x8, qf[m][ks]), kf, s[m][nt]);
      }

    // causal mask (diagonal-touching chunks; fully-masked chunks -> p=0)
    if (t0 + 31 > qbase + wv * 32) {
#pragma unroll
      for (int m = 0; m < 2; m++)
#pragma unroll
        for (int nt = 0; nt < 2; nt++)
#pragma unroll
          for (int reg = 0; reg < 4; reg++) {
            int kidx = t0 + nt * 16 + ln;
            int qidx = qbase + wv * 32 + m * 16 + quad * 4 + reg;
            if (kidx > qidx) s[m][nt][reg] = -1e30f;
          }
    }

    // p = exp2(s) -> bf16 -> wave-private LDS (C->A layout round-trip)
#pragma unroll
    for (int m = 0; m < 2; m++)
#pragma unroll
      for (int nt = 0; nt < 2; nt++)
#pragma unroll
        for (int reg = 0; reg < 4; reg++) {
          float pv = __builtin_amdgcn_exp2f(s[m][nt][reg]);
          Pl[(wv * 32 + m * 16 + quad * 4 + reg) * 40 + nt * 16 + ln] = f2bf(pv);
        }

    // PV + l accumulation; V frag (h = nh*16+ln, granule gt = quad, swizzled)
    s16x8 pa[2];
#pragma unroll
    for (int m = 0; m < 2; m++)
      pa[m] = __builtin_bit_cast(s16x8,
          *(const u32x4*)&Pl[(wv * 32 + m * 16 + ln) * 40 + quad * 8]);
#pragma unroll
    for (int nh = 0; nh < 8; nh++) {
      int h = nh * 16 + ln;
      int gts = quad ^ ((h >> 1) & 3);
      s16x8 vf = __builtin_bit_cast(s16x8,
          *(const u32x4*)&kvb[cur][4096 + (h * 4 + gts) * 8]);
#pragma unroll
      for (int m = 0; m < 2; m++)
        o[m][nh] = mfma16(pa[m], vf, o[m][nh]);
    }
#pragma unroll
    for (int m = 0; m < 2; m++)
      lacc[m] = mfma16(pa[m], onesb, lacc[m]);
  }

  // epilogue: bf16 unnormalized partial + fp32 row sums
  unsigned short* po = Po + (size_t)id * 16384;
#pragma unroll
  for (int m = 0; m < 2; m++) {
#pragma unroll
    for (int reg = 0; reg < 4; reg++) {
      int rowl = wv * 32 + m * 16 + quad * 4 + reg;
#pragma unroll
      for (int nh = 0; nh < 8; nh++)
        po[rowl * 128 + nh * 16 + ln] = f2bf(o[m][nh][reg]);
      if (ln == 0) Plr[id * 128 + rowl] = lacc[m][reg];
    }
  }
}

// ============ kernel 4: combine bf16 partials (pure sums, coalesced) ========
__global__ __launch_bounds__(256) void combine_k(const unsigned short* __restrict__ Po,
    const float* __restrict__ Plr, float* __restrict__ out) {
  const int id = blockIdx.x;
  const int tileid = id >> 2, quarter = id & 3;
  const int qt = tileid & 31;
  const int b = tileid >> 5;
  const int a_ = qt >> 2, r_ = qt & 3;
  const int base = b * 144 + 2 * a_ * (a_ + 1) + r_ * (a_ + 1);
  const int nseg = a_ + 1;
  const int tid = threadIdx.x;
#pragma unroll
  for (int i = 0; i < 2; i++) {
    int g = quarter * 512 + i * 256 + tid;   // granule of 8 elems; 2048/tile
    int row = g >> 4;
    float acc[8] = {0.f, 0.f, 0.f, 0.f, 0.f, 0.f, 0.f, 0.f};
    float L = 0.f;
    for (int s = 0; s < nseg; s++) {
      u32x4 u = *(const u32x4*)(Po + (size_t)(base + s) * 16384 + g * 8);
      L += Plr[(base + s) * 128 + row];
      acc[0] += __builtin_bit_cast(float, u.x << 16);
      acc[1] += __builtin_bit_cast(float, u.x & 0xffff0000u);
      acc[2] += __builtin_bit_cast(float, u.y << 16);
      acc[3] += __builtin_bit_cast(float, u.y & 0xffff0000u);
      acc[4] += __builtin_bit_cast(float, u.z << 16);
      acc[5] += __builtin_bit_cast(float, u.z & 0xffff0000u);
      acc[6] += __builtin_bit_cast(float, u.w << 16);
      acc[7] += __builtin_bit_cast(float, u.w & 0xffff0000u);
    }
    float inv = 1.f / L;
    float* op = out + (size_t)tileid * 16384 + g * 8;
    f32x4 o0 = {acc[0] * inv, acc[1] * inv, acc[2] * inv, acc[3] * inv};
    f32x4 o1 = {acc[4] * inv, acc[5] * inv, acc[6] * inv, acc[7] * inv};
    *(f32x4*)op = o0;
    *(f32x4*)(op + 4) = o1;
  }
}

// ============ launch ============
extern "C" void kernel_launch(void* const* d_in, const int* in_sizes, int n_in,
                              void* d_out, int out_size, void* d_ws, size_t ws_size,
                              hipStream_t stream) {
  const float* x  = (const float*)d_in[0];
  const float* Wq = (const float*)d_in[1];
  const float* bq = (const float*)d_in[2];
  const float* Wk = (const float*)d_in[3];
  const float* bk = (const float*)d_in[4];
  const float* Wv = (const float*)d_in[5];
  const float* bv = (const float*)d_in[6];
  float* out = (float*)d_out;

  char* wsb = (char*)d_ws;
  unsigned short* Wt  = (unsigned short*)wsb;                 // 768 KB (tiled W)
  unsigned short* Qg  = (unsigned short*)(wsb + 786432);      // 4 MB
  unsigned short* KVg = (unsigned short*)(wsb + 4980736);     // 8 MB (512 x 16KB tiles)
  unsigned short* Po  = (unsigned short*)(wsb + 13369344);    // 18.9 MB (576 slots, bf16)
  float* Plr = (float*)(wsb + 32243712);                      // 288 KB

  wconv_k<<<dim3(384), dim3(256), 0, stream>>>(Wq, Wk, Wv, Wt);
  proj_k<<<dim3(512), dim3(256), 0, stream>>>(x, bq, bk, bv, Wt, Qg, KVg);
  attn_k<<<dim3(576), dim3(256), 0, stream>>>(Qg, KVg, Po, Plr);
  combine_k<<<dim3(512), dim3(256), 0, stream>>>(Po, Plr, out);
}